// Round 1
// baseline (76.380 us; speedup 1.0000x reference)
//
#include <hip/hip_runtime.h>
#include <math.h>

#define DD      4096
#define SSHIFT  64
#define WW      129                 // 2*S + 1 shifts
#define PADN    (DD + 2 * SSHIFT)   // 4224: zero-padded xh
#define NPART   4                   // shift-partitions per (b,c) pair
#define BLOCKN  256

// One block handles one (b, c, part) triple: computes the per-shift Pearson
// corr for shifts w = part + 4*wv + 16*k and writes the partial max.
__global__ __launch_bounds__(BLOCKN) void spl_main(
        const float* __restrict__ x, const float* __restrict__ y,
        float* __restrict__ partial) {
    const int blk  = blockIdx.x;          // 0 .. 128*NPART-1
    const int bc   = blk >> 2;            // (b,c) pair id
    const int part = blk & (NPART - 1);
    const int b = bc >> 1;
    const int c = bc & 1;
    // jnp.flip(x, axis=1) with C=2: output channel c <- input channel 1-c
    const float* xp = x + (size_t)(b * 2 + (1 - c)) * DD;
    const float* yp = y + (size_t)(b * 2 + c) * DD;

    __shared__ float xhp[PADN];   // zero-padded, normalized, hann-windowed x
    __shared__ float red[12];

    const int tid  = threadIdx.x;
    const int lane = tid & 63;
    const int wv   = tid >> 6;

    // zero the pad regions [0,S) and [S+D, PADN)
    if (tid < SSHIFT) {
        xhp[tid] = 0.0f;
        xhp[SSHIFT + DD + tid] = 0.0f;
    }

    // ---- pass 1: min/max of x, sum of y ----
    float xmn = 3.0e38f, xmx = -3.0e38f, ysum = 0.0f;
    for (int d = tid; d < DD; d += BLOCKN) {
        float xv = xp[d];
        xmn = fminf(xmn, xv);
        xmx = fmaxf(xmx, xv);
        ysum += yp[d];
    }
    #pragma unroll
    for (int off = 32; off > 0; off >>= 1) {
        xmn  = fminf(xmn, __shfl_down(xmn, off, 64));
        xmx  = fmaxf(xmx, __shfl_down(xmx, off, 64));
        ysum += __shfl_down(ysum, off, 64);
    }
    if (lane == 0) { red[wv] = xmn; red[4 + wv] = xmx; red[8 + wv] = ysum; }
    __syncthreads();
    xmn = fminf(fminf(red[0], red[1]), fminf(red[2], red[3]));
    xmx = fmaxf(fmaxf(red[4], red[5]), fmaxf(red[6], red[7]));
    const float ymean = (red[8] + red[9] + red[10] + red[11]) * (1.0f / (float)DD);
    const float inv   = 2.0f / (xmx - xmn);
    __syncthreads();   // all red[] reads complete before later reuse

    // ---- pass 2: xh = (2*(x-min)/(max-min) - 1) * hann  into padded LDS ----
    for (int d = tid; d < DD; d += BLOCKN) {
        float h = 0.5f * (1.0f - cosf((float)d * (6.2831853071795864769f / (float)DD)));
        xhp[SSHIFT + d] = (inv * (xp[d] - xmn) - 1.0f) * h;
    }

    // ---- centered y in per-lane registers (each wave holds the full vector:
    //      lane holds yc[64*i + lane], i = 0..63) + syy ----
    float ycr[64];
    float syy = 0.0f;
    #pragma unroll
    for (int i = 0; i < 64; ++i) {
        float yv = yp[64 * i + lane] - ymean;
        ycr[i] = yv;
        syy = fmaf(yv, yv, syy);
    }
    #pragma unroll
    for (int off = 32; off > 0; off >>= 1) syy += __shfl_down(syy, off, 64);
    syy = __shfl(syy, 0, 64);

    __syncthreads();   // xhp fully written (incl. pads)

    // ---- shift loop: cross, sx, sxx per shift; Pearson; running max ----
    float vmax = -3.0e38f;
    for (int w = part + NPART * wv; w < WW; w += NPART * 4) {
        float cr = 0.0f, sx = 0.0f, sxx = 0.0f;
        #pragma unroll
        for (int i = 0; i < 64; ++i) {
            float xv = xhp[64 * i + lane + w];
            cr  = fmaf(xv, ycr[i], cr);
            sx += xv;
            sxx = fmaf(xv, xv, sxx);
        }
        #pragma unroll
        for (int off = 32; off > 0; off >>= 1) {
            cr  += __shfl_down(cr, off, 64);
            sx  += __shfl_down(sx, off, 64);
            sxx += __shfl_down(sxx, off, 64);
        }
        if (lane == 0) {
            // var_x = sxx - sx^2/D ; corr = cross / sqrt(var_x * syy)
            float varx = sxx - sx * sx * (1.0f / (float)DD);
            float corr = cr / sqrtf(varx * syy);
            vmax = fmaxf(vmax, corr);
        }
    }
    if (lane == 0) red[wv] = vmax;
    __syncthreads();
    if (tid == 0)
        partial[blk] = fmaxf(fmaxf(red[0], red[1]), fmaxf(red[2], red[3]));
}

// Final: values[b][c] = max over parts; scores[b] = sqrt(v0^2+v1^2);
// out = -mean(scores)
__global__ void spl_final(const float* __restrict__ partial,
                          float* __restrict__ out) {
    const int b = threadIdx.x;   // 64 threads, one per batch row
    float v0 = -3.0e38f, v1 = -3.0e38f;
    #pragma unroll
    for (int p = 0; p < NPART; ++p) {
        v0 = fmaxf(v0, partial[(b * 2 + 0) * NPART + p]);
        v1 = fmaxf(v1, partial[(b * 2 + 1) * NPART + p]);
    }
    float s = sqrtf(v0 * v0 + v1 * v1);
    #pragma unroll
    for (int off = 32; off > 0; off >>= 1) s += __shfl_down(s, off, 64);
    if (b == 0) out[0] = -s * (1.0f / 64.0f);
}

extern "C" void kernel_launch(void* const* d_in, const int* in_sizes, int n_in,
                              void* d_out, int out_size, void* d_ws, size_t ws_size,
                              hipStream_t stream) {
    const float* x = (const float*)d_in[0];
    const float* y = (const float*)d_in[1];
    float* out     = (float*)d_out;
    float* partial = (float*)d_ws;   // 128*NPART floats = 2 KB

    spl_main<<<dim3(128 * NPART), dim3(BLOCKN), 0, stream>>>(x, y, partial);
    spl_final<<<dim3(1), dim3(64), 0, stream>>>(partial, out);
}

// Round 2
// 71.504 us; speedup vs baseline: 1.0682x; 1.0682x over previous
//
#include <hip/hip_runtime.h>
#include <math.h>

#define DD      4096
#define SSHIFT  64
#define WW      129                 // 2*S + 1 shifts
#define PADN    (DD + 2 * SSHIFT)   // 4224: zero-padded xh
#define NPART   4                   // shift-partitions per (b,c) pair
#define BLOCKN  256

// One block handles one (b, c, part) triple. All shifts of this block are
// w ≡ part (mod 4), so LDS holds xs[m] = xhp[m + part] and every shift reads
// 16B-aligned float4 (ds_read_b128). sx/sxx come from edge prefix sums.
__global__ __launch_bounds__(BLOCKN) void spl_main(
        const float* __restrict__ x, const float* __restrict__ y,
        float* __restrict__ partial) {
    const int blk  = blockIdx.x;          // 0 .. 128*NPART-1
    const int bc   = blk >> 2;            // (b,c) pair id
    const int part = blk & (NPART - 1);
    const int b = bc >> 1;
    const int c = bc & 1;
    // jnp.flip(x, axis=1) with C=2: output channel c <- input channel 1-c
    const float* xp = x + (size_t)(b * 2 + (1 - c)) * DD;
    const float* yp = y + (size_t)(b * 2 + c) * DD;

    __shared__ __align__(16) float xs[PADN];  // xs[m] = xhp[m + part]
    __shared__ float P0s[65], P0q[65], Qs[65], Qq[65];
    __shared__ float red[20];
    __shared__ float wred[4];

    const int tid  = threadIdx.x;
    const int lane = tid & 63;
    const int wv   = tid >> 6;

    // ---- pass 1: min/max of x, sum of y (float4 loads) ----
    const float4* xp4 = (const float4*)xp;
    const float4* yp4 = (const float4*)yp;
    float xmn = 3.0e38f, xmx = -3.0e38f, ysum = 0.0f;
    #pragma unroll
    for (int it = 0; it < DD / 4 / BLOCKN; ++it) {
        int d4 = tid + it * BLOCKN;
        float4 xv = xp4[d4];
        xmn = fminf(xmn, fminf(fminf(xv.x, xv.y), fminf(xv.z, xv.w)));
        xmx = fmaxf(xmx, fmaxf(fmaxf(xv.x, xv.y), fmaxf(xv.z, xv.w)));
        float4 yv = yp4[d4];
        ysum += (yv.x + yv.y) + (yv.z + yv.w);
    }
    #pragma unroll
    for (int off = 32; off > 0; off >>= 1) {
        xmn  = fminf(xmn, __shfl_down(xmn, off, 64));
        xmx  = fmaxf(xmx, __shfl_down(xmx, off, 64));
        ysum += __shfl_down(ysum, off, 64);
    }
    if (lane == 0) { red[wv] = xmn; red[4 + wv] = xmx; red[8 + wv] = ysum; }
    __syncthreads();
    xmn = fminf(fminf(red[0], red[1]), fminf(red[2], red[3]));
    xmx = fmaxf(fmaxf(red[4], red[5]), fmaxf(red[6], red[7]));
    const float ymean = (red[8] + red[9] + red[10] + red[11]) * (1.0f / (float)DD);
    const float inv   = 2.0f / (xmx - xmn);

    // ---- fill xs[m] = xhp[m+part]; accumulate Stot, Sqtot over xh ----
    // hann: 0.5*(1-cos(2*pi*d/D)) via v_cos_f32 (input in revolutions)
    float ssum = 0.0f, ssq = 0.0f;
    for (int m = tid; m < PADN; m += BLOCKN) {
        int d = m + part - SSHIFT;
        float v = 0.0f;
        if (d >= 0 && d < DD) {
            float h = 0.5f * (1.0f - __builtin_amdgcn_cosf((float)d * (1.0f / (float)DD)));
            v = (inv * (xp[d] - xmn) - 1.0f) * h;
        }
        xs[m] = v;
        ssum += v;
        ssq  = fmaf(v, v, ssq);
    }
    #pragma unroll
    for (int off = 32; off > 0; off >>= 1) {
        ssum += __shfl_down(ssum, off, 64);
        ssq  += __shfl_down(ssq,  off, 64);
    }
    if (lane == 0) { red[12 + wv] = ssum; red[16 + wv] = ssq; }

    // ---- centered y in registers, layout matching b128 lanes:
    //      yc4[i] = yc[256*i + 4*lane .. +3] ----
    float4 yc4[16];
    float syy = 0.0f;
    #pragma unroll
    for (int i = 0; i < 16; ++i) {
        float4 v = yp4[64 * i + lane];
        v.x -= ymean; v.y -= ymean; v.z -= ymean; v.w -= ymean;
        yc4[i] = v;
        syy = fmaf(v.x, v.x, fmaf(v.y, v.y, fmaf(v.z, v.z, fmaf(v.w, v.w, syy))));
    }
    #pragma unroll
    for (int off = 32; off > 0; off >>= 1) syy += __shfl_down(syy, off, 64);
    syy = __shfl(syy, 0, 64);

    __syncthreads();   // xs + red[12..19] complete
    const float Stot  = (red[12] + red[13]) + (red[14] + red[15]);
    const float Sqtot = (red[16] + red[17]) + (red[18] + red[19]);

    // ---- edge prefix sums (head: xh[0..63], tail: xh[4032..4095]) ----
    if (wv == 0) {
        float v = xs[SSHIFT - part + lane];            // xh[lane]
        float s = v, sq = v * v, vsq = sq;
        #pragma unroll
        for (int off = 1; off < 64; off <<= 1) {
            float t  = __shfl_up(s,  off, 64);
            float tq = __shfl_up(sq, off, 64);
            if (lane >= off) { s += t; sq += tq; }
        }
        P0s[lane + 1] = s; P0q[lane + 1] = sq;
        if (lane == 0) { P0s[0] = 0.0f; P0q[0] = 0.0f; }
        (void)vsq;
    } else if (wv == 1) {
        float v = xs[DD - part + lane];                // xh[4032 + lane]
        float s = v, sq = v * v;
        #pragma unroll
        for (int off = 1; off < 64; off <<= 1) {
            float t  = __shfl_up(s,  off, 64);
            float tq = __shfl_up(sq, off, 64);
            if (lane >= off) { s += t; sq += tq; }
        }
        float Ts = __shfl(s, 63, 64), Tq = __shfl(sq, 63, 64);
        Qs[lane] = Ts - (s - v);                       // sum over l >= lane
        Qq[lane] = Tq - (sq - v * v);
        if (lane == 63) { Qs[64] = 0.0f; Qq[64] = 0.0f; }
    }
    __syncthreads();

    // ---- shift loop: w = part + 4*wv + 16*k; q = (w-part)/4 = wv + 4*k ----
    const float4* xs4 = (const float4*)xs;
    const int w0 = part + 4 * wv;
    float vmax = -3.0e38f;
    #pragma unroll
    for (int k = 0; k < 9; ++k) {
        const int w = w0 + 16 * k;
        if (w < WW) {
            const int q = wv + 4 * k;
            float cr = 0.0f;
            #pragma unroll
            for (int i = 0; i < 16; ++i) {
                float4 xv = xs4[64 * i + lane + q];
                cr = fmaf(xv.x, yc4[i].x,
                     fmaf(xv.y, yc4[i].y,
                     fmaf(xv.z, yc4[i].z,
                     fmaf(xv.w, yc4[i].w, cr))));
            }
            #pragma unroll
            for (int off = 32; off > 0; off >>= 1) cr += __shfl_down(cr, off, 64);
            if (lane == 0) {
                int hidx = (w > SSHIFT) ? (w - SSHIFT) : 0;
                int tidx = (w < 64) ? w : 64;
                float sx  = Stot  - P0s[hidx] - Qs[tidx];
                float sxx = Sqtot - P0q[hidx] - Qq[tidx];
                float varx = sxx - sx * sx * (1.0f / (float)DD);
                float corr = cr / sqrtf(varx * syy);
                vmax = fmaxf(vmax, corr);
            }
        }
    }
    if (lane == 0) wred[wv] = vmax;
    __syncthreads();
    if (tid == 0)
        partial[blk] = fmaxf(fmaxf(wred[0], wred[1]), fmaxf(wred[2], wred[3]));
}

// Final: values[b][c] = max over parts; scores[b] = sqrt(v0^2+v1^2);
// out = -mean(scores)
__global__ void spl_final(const float* __restrict__ partial,
                          float* __restrict__ out) {
    const int b = threadIdx.x;   // 64 threads, one per batch row
    float v0 = -3.0e38f, v1 = -3.0e38f;
    #pragma unroll
    for (int p = 0; p < NPART; ++p) {
        v0 = fmaxf(v0, partial[(b * 2 + 0) * NPART + p]);
        v1 = fmaxf(v1, partial[(b * 2 + 1) * NPART + p]);
    }
    float s = sqrtf(v0 * v0 + v1 * v1);
    #pragma unroll
    for (int off = 32; off > 0; off >>= 1) s += __shfl_down(s, off, 64);
    if (b == 0) out[0] = -s * (1.0f / 64.0f);
}

extern "C" void kernel_launch(void* const* d_in, const int* in_sizes, int n_in,
                              void* d_out, int out_size, void* d_ws, size_t ws_size,
                              hipStream_t stream) {
    const float* x = (const float*)d_in[0];
    const float* y = (const float*)d_in[1];
    float* out     = (float*)d_out;
    float* partial = (float*)d_ws;   // 128*NPART floats = 2 KB

    spl_main<<<dim3(128 * NPART), dim3(BLOCKN), 0, stream>>>(x, y, partial);
    spl_final<<<dim3(1), dim3(64), 0, stream>>>(partial, out);
}

// Round 3
// 69.754 us; speedup vs baseline: 1.0950x; 1.0251x over previous
//
#include <hip/hip_runtime.h>
#include <math.h>

#define DD      4096
#define WW      129                 // 2*S+1 shifts
#define XSN     4240                // 64 left pad + 4096 + 80 right pad (1060 float4)
#define NP      4                   // blocks per (b,c) pair
#define BLOCKN  256

// One block per (b,c,p). Unrotated padded xh in LDS; wave wv computes shift
// GROUP g = p + 4*wv (+16 for p=0,wv=0): 8 shifts per group via a 12-float
// sliding window from 3 contiguous ds_read_b128 (base 64i+lane+2g is always
// float4-aligned). yc register-cached per lane. sx/sxx from edge prefix sums.
__global__ __launch_bounds__(BLOCKN) void spl_main(
        const float* __restrict__ x, const float* __restrict__ y,
        float* __restrict__ partial) {
    const int blk = blockIdx.x;           // 0 .. 128*NP-1
    const int bc  = blk >> 2, p = blk & 3;
    const int b   = bc >> 1,  c = bc & 1;
    // jnp.flip(x, axis=1), C=2: output channel c <- x channel 1-c
    const float* xp = x + (size_t)(b * 2 + (1 - c)) * DD;
    const float* yp = y + (size_t)(b * 2 + c) * DD;
    const float4* xp4 = (const float4*)xp;
    const float4* yp4 = (const float4*)yp;

    __shared__ __align__(16) float xs[XSN];   // xs = xhp (padded, unrotated)
    __shared__ float P0s[65], P0q[65], Qs[65], Qq[65];
    __shared__ float red[20];
    __shared__ float wred[4];

    const int tid = threadIdx.x, lane = tid & 63, wv = tid >> 6;

    // zero pads: float4 idx [0,16) and [1040,1060) — disjoint from xh region
    if (tid < 36) {
        int i4 = (tid < 16) ? tid : (1024 + tid);
        ((float4*)xs)[i4] = make_float4(0.f, 0.f, 0.f, 0.f);
    }

    // ---- pass 1: min/max of x, sum of y ----
    float xmn = 3.0e38f, xmx = -3.0e38f, ysum = 0.0f;
    #pragma unroll
    for (int it = 0; it < 4; ++it) {
        float4 xv = xp4[tid + 256 * it];
        float4 yv = yp4[tid + 256 * it];
        xmn = fminf(xmn, fminf(fminf(xv.x, xv.y), fminf(xv.z, xv.w)));
        xmx = fmaxf(xmx, fmaxf(fmaxf(xv.x, xv.y), fmaxf(xv.z, xv.w)));
        ysum += (yv.x + yv.y) + (yv.z + yv.w);
    }
    #pragma unroll
    for (int off = 32; off > 0; off >>= 1) {
        xmn  = fminf(xmn, __shfl_down(xmn, off, 64));
        xmx  = fmaxf(xmx, __shfl_down(xmx, off, 64));
        ysum += __shfl_down(ysum, off, 64);
    }
    if (lane == 0) { red[wv] = xmn; red[4 + wv] = xmx; red[8 + wv] = ysum; }
    __syncthreads();
    xmn = fminf(fminf(red[0], red[1]), fminf(red[2], red[3]));
    xmx = fmaxf(fmaxf(red[4], red[5]), fmaxf(red[6], red[7]));
    const float ymean = (red[8] + red[9] + red[10] + red[11]) * (1.0f / (float)DD);
    const float a   = 2.0f / (xmx - xmn);
    const float bsh = -a * xmn - 1.0f;

    // ---- pass 2: xh = (a*x+bsh)*hann -> xs[64+d] via ds_write_b128 ----
    float ssum = 0.0f, ssq = 0.0f;
    #pragma unroll
    for (int it = 0; it < 4; ++it) {
        int i4 = tid + 256 * it;            // float4 index over 1024
        float4 xv = xp4[i4];
        float fd = (float)(4 * i4);
        float4 h;
        h.x = 0.5f - 0.5f * __builtin_amdgcn_cosf((fd + 0.0f) * (1.0f / (float)DD));
        h.y = 0.5f - 0.5f * __builtin_amdgcn_cosf((fd + 1.0f) * (1.0f / (float)DD));
        h.z = 0.5f - 0.5f * __builtin_amdgcn_cosf((fd + 2.0f) * (1.0f / (float)DD));
        h.w = 0.5f - 0.5f * __builtin_amdgcn_cosf((fd + 3.0f) * (1.0f / (float)DD));
        float4 v;
        v.x = fmaf(a, xv.x, bsh) * h.x;
        v.y = fmaf(a, xv.y, bsh) * h.y;
        v.z = fmaf(a, xv.z, bsh) * h.z;
        v.w = fmaf(a, xv.w, bsh) * h.w;
        ((float4*)(xs + 64))[i4] = v;
        ssum += (v.x + v.y) + (v.z + v.w);
        ssq = fmaf(v.x, v.x, fmaf(v.y, v.y, fmaf(v.z, v.z, fmaf(v.w, v.w, ssq))));
    }

    // ---- centered y in regs: yc4[i] = yc[256*i + 4*lane .. +3]; syy/wave ----
    float4 yc4[16];
    float syy = 0.0f;
    #pragma unroll
    for (int i = 0; i < 16; ++i) {
        float4 v = yp4[64 * i + lane];
        v.x -= ymean; v.y -= ymean; v.z -= ymean; v.w -= ymean;
        yc4[i] = v;
        syy = fmaf(v.x, v.x, fmaf(v.y, v.y, fmaf(v.z, v.z, fmaf(v.w, v.w, syy))));
    }
    #pragma unroll
    for (int off = 32; off > 0; off >>= 1) {
        ssum += __shfl_down(ssum, off, 64);
        ssq  += __shfl_down(ssq,  off, 64);
        syy  += __shfl_down(syy,  off, 64);
    }
    if (lane == 0) { red[12 + wv] = ssum; red[16 + wv] = ssq; }
    syy = __shfl(syy, 0, 64);

    // ---- edge prefix scans (recomputed xh, independent of xs) ----
    if (wv == 0) {                        // head: xh[0..63]
        int d = lane;
        float h = 0.5f - 0.5f * __builtin_amdgcn_cosf((float)d * (1.0f / (float)DD));
        float v = fmaf(a, xp[d], bsh) * h;
        float s = v, sq = v * v;
        #pragma unroll
        for (int off = 1; off < 64; off <<= 1) {
            float t  = __shfl_up(s,  off, 64);
            float tq = __shfl_up(sq, off, 64);
            if (lane >= off) { s += t; sq += tq; }
        }
        P0s[lane + 1] = s; P0q[lane + 1] = sq;
        if (lane == 0) { P0s[0] = 0.0f; P0q[0] = 0.0f; }
    } else if (wv == 1) {                 // tail: xh[4032..4095]
        int d = 4032 + lane;
        float h = 0.5f - 0.5f * __builtin_amdgcn_cosf((float)d * (1.0f / (float)DD));
        float v = fmaf(a, xp[d], bsh) * h;
        float s = v, sq = v * v;
        #pragma unroll
        for (int off = 1; off < 64; off <<= 1) {
            float t  = __shfl_up(s,  off, 64);
            float tq = __shfl_up(sq, off, 64);
            if (lane >= off) { s += t; sq += tq; }
        }
        float Ts = __shfl(s, 63, 64), Tq = __shfl(sq, 63, 64);
        Qs[lane] = Ts - (s - v);          // sum over l >= lane
        Qq[lane] = Tq - (sq - v * v);
        if (lane == 63) { Qs[64] = 0.0f; Qq[64] = 0.0f; }
    }
    __syncthreads();
    const float Stot  = (red[12] + red[13]) + (red[14] + red[15]);
    const float Sqtot = (red[16] + red[17]) + (red[18] + red[19]);

    // ---- compute: groups of 8 shifts via 12-float sliding window ----
    const float4* xs4 = (const float4*)xs;
    float vmax = -3.0e38f;
    for (int g = p + 4 * wv; g <= 16; g += 16) {   // 1 group/wave (+1 once)
        float cr[8];
        #pragma unroll
        for (int j = 0; j < 8; ++j) cr[j] = 0.0f;
        const int A0 = lane + 2 * g;
        #pragma unroll
        for (int i = 0; i < 16; ++i) {
            int A = 64 * i + A0;
            float4 x0 = xs4[A], x1 = xs4[A + 1], x2 = xs4[A + 2];
            float wnd[12] = { x0.x, x0.y, x0.z, x0.w,
                              x1.x, x1.y, x1.z, x1.w,
                              x2.x, x2.y, x2.z, x2.w };
            float4 yv = yc4[i];
            #pragma unroll
            for (int j = 0; j < 8; ++j)
                cr[j] = fmaf(yv.x, wnd[j],
                        fmaf(yv.y, wnd[j + 1],
                        fmaf(yv.z, wnd[j + 2],
                        fmaf(yv.w, wnd[j + 3], cr[j]))));
        }
        #pragma unroll
        for (int off = 32; off > 0; off >>= 1) {
            #pragma unroll
            for (int j = 0; j < 8; ++j) cr[j] += __shfl_down(cr[j], off, 64);
        }
        if (lane == 0) {
            #pragma unroll
            for (int j = 0; j < 8; ++j) {
                int w = 8 * g + j;
                if (w < WW) {
                    int hidx = (w > 64) ? (w - 64) : 0;
                    int tidx = (w < 64) ? w : 64;
                    float sx   = Stot  - P0s[hidx] - Qs[tidx];
                    float sxx  = Sqtot - P0q[hidx] - Qq[tidx];
                    float varx = sxx - sx * sx * (1.0f / (float)DD);
                    float corr = cr[j] / sqrtf(varx * syy);
                    vmax = fmaxf(vmax, corr);
                }
            }
        }
    }
    if (lane == 0) wred[wv] = vmax;
    __syncthreads();
    if (tid == 0)
        partial[blk] = fmaxf(fmaxf(wred[0], wred[1]), fmaxf(wred[2], wred[3]));
}

// values[b][c] = max over NP partials; scores[b] = sqrt(v0^2+v1^2);
// out = -mean(scores)
__global__ void spl_final(const float* __restrict__ partial,
                          float* __restrict__ out) {
    const int b = threadIdx.x;   // 64 threads, one per batch row
    float v0 = -3.0e38f, v1 = -3.0e38f;
    #pragma unroll
    for (int pp = 0; pp < NP; ++pp) {
        v0 = fmaxf(v0, partial[(b * 2 + 0) * NP + pp]);
        v1 = fmaxf(v1, partial[(b * 2 + 1) * NP + pp]);
    }
    float s = sqrtf(v0 * v0 + v1 * v1);
    #pragma unroll
    for (int off = 32; off > 0; off >>= 1) s += __shfl_down(s, off, 64);
    if (b == 0) out[0] = -s * (1.0f / 64.0f);
}

extern "C" void kernel_launch(void* const* d_in, const int* in_sizes, int n_in,
                              void* d_out, int out_size, void* d_ws, size_t ws_size,
                              hipStream_t stream) {
    const float* x = (const float*)d_in[0];
    const float* y = (const float*)d_in[1];
    float* out     = (float*)d_out;
    float* partial = (float*)d_ws;   // 128*NP floats = 2 KB

    spl_main<<<dim3(128 * NP), dim3(BLOCKN), 0, stream>>>(x, y, partial);
    spl_final<<<dim3(1), dim3(64), 0, stream>>>(partial, out);
}